// Round 4
// baseline (416.164 us; speedup 1.0000x reference)
//
#include <hip/hip_runtime.h>
#include <hip/hip_bf16.h>
#include <cstdint>
#include <cstddef>

#define E_EDGES 320000
#define NN 10000
#define NRELS 40
#define NB 30
#define HID 100
#define NHTOT (NN*HID)       // 1,000,000
#define R2 41                // 40 rels + root2 slot
#define KTOT 4224            // 41*100 = 4100 packed, padded to 33*128
#define NROWS_PAD 10048      // 628 row-groups * 16 rows
#define SPLITK 7             // 132 kb-steps -> 19 per gy (last 18)
#define KB_PER 19

typedef short bf16x8 __attribute__((ext_vector_type(8)));
typedef float f32x4 __attribute__((ext_vector_type(4)));

__device__ inline ushort f2bf(float f) {
  uint x = __float_as_uint(f);
  return (ushort)((x + 0x7fffu + ((x >> 16) & 1u)) >> 16);
}
__device__ inline float bflo(uint u) { return __uint_as_float(u << 16); }
__device__ inline float bfhi(uint u) { return __uint_as_float(u & 0xffff0000u); }

// ---------------------------------------------------------------- edge meta
__global__ void k_count(const int* __restrict__ dst, const int* __restrict__ et,
                        int* __restrict__ cnt_nr, int* __restrict__ deg) {
  int e = blockIdx.x * blockDim.x + threadIdx.x;
  if (e >= E_EDGES) return;
  int d = dst[e], r = et[e];
  atomicAdd(&cnt_nr[d * NRELS + r], 1);
  atomicAdd(&deg[d], 1);
}

__global__ void k_scan(const int* __restrict__ deg, int* __restrict__ rowptr) {
  __shared__ int ssum[256];
  int t = threadIdx.x;
  const int per = (NN + 255) / 256;
  int base = t * per;
  int s = 0;
  for (int k = 0; k < per; ++k) { int i = base + k; if (i < NN) s += deg[i]; }
  ssum[t] = s; __syncthreads();
  for (int off = 1; off < 256; off <<= 1) {
    int v = (t >= off) ? ssum[t - off] : 0;
    __syncthreads();
    ssum[t] += v;
    __syncthreads();
  }
  int pre = (t == 0) ? 0 : ssum[t - 1];
  for (int k = 0; k < per; ++k) {
    int i = base + k;
    if (i < NN) { rowptr[i] = pre; pre += deg[i]; }
  }
  if (t == 255) rowptr[NN] = ssum[255];
}

__global__ void k_bucket(const int* __restrict__ src, const int* __restrict__ dst,
                         const int* __restrict__ et, const int* __restrict__ rowptr,
                         int* __restrict__ fill, int* __restrict__ ebuf) {
  int e = blockIdx.x * blockDim.x + threadIdx.x;
  if (e >= E_EDGES) return;
  int d = dst[e];
  int pos = rowptr[d] + atomicAdd(&fill[d], 1);
  ebuf[pos] = (src[e] << 6) | et[e];
}

// ---------------------------------------------------------------- W1 (bf16, all 40 rels)
// launch_bounds(256,2): allow ~128 VGPRs so v[30] float2 stays in registers
// (default 64-VGPR cap spilled it to scratch -> 157us latency-bound, r3 counters)
__global__ __launch_bounds__(256, 2) void k_w1b(const float* __restrict__ comp1,
                                                const float* __restrict__ basis1,
                                                uint* __restrict__ W1bf) {
  int i2 = blockIdx.x * 256 + threadIdx.x;
  if (i2 >= NHTOT / 2) return;
  int b0 = blockIdx.x % NB;   // stagger stream order: break 4MB-stride set aliasing
  float2 v[NB];
#pragma unroll
  for (int j = 0; j < NB; ++j) {
    int b = b0 + j; if (b >= NB) b -= NB;
    v[j] = ((const float2*)basis1)[(size_t)b * (NHTOT / 2) + i2];
  }
  for (int r = 0; r < NRELS; ++r) {
    float ax = 0.f, ay = 0.f;
#pragma unroll
    for (int j = 0; j < NB; ++j) {
      int b = b0 + j; if (b >= NB) b -= NB;
      float c = comp1[r * NB + b];
      ax += c * v[j].x; ay += c * v[j].y;
    }
    W1bf[(size_t)r * (NHTOT / 2) + i2] = (uint)f2bf(ax) | ((uint)f2bf(ay) << 16);
  }
}

// ---------------------------------------------------------------- W2 fp32 then packed Bt bf16
__global__ void k_w2(const float* __restrict__ comp2, const float* __restrict__ basis2,
                     float* __restrict__ W2f) {
  int i = blockIdx.x * 256 + threadIdx.x;
  if (i >= HID * HID) return;
  float v[NB];
#pragma unroll
  for (int b = 0; b < NB; ++b) v[b] = basis2[b * HID * HID + i];
  for (int r = 0; r < NRELS; ++r) {
    float a = 0.f;
#pragma unroll
    for (int b = 0; b < NB; ++b) a += comp2[r * NB + b] * v[b];
    W2f[r * HID * HID + i] = a;
  }
}

// Bt[col][kk] packed K: kk = r*100 + k  (r<40: W2f[r][k][col], r==40: root2[k][col])
__global__ void k_bt(const float* __restrict__ W2f, const float* __restrict__ root2,
                     ushort* __restrict__ Bt) {
  int i = blockIdx.x * 256 + threadIdx.x;
  if (i >= 112 * KTOT) return;
  int col = i / KTOT, kk = i - col * KTOT;
  float v = 0.f;
  if (kk < R2 * HID && col < HID) {
    int r = kk / HID, k = kk - r * HID;
    v = (r < NRELS) ? W2f[(r * HID + k) * HID + col] : root2[k * HID + col];
  }
  Bt[i] = f2bf(v);
}

// ---------------------------------------------------------------- conv1 aggregate
__global__ void k_agg1(const int* __restrict__ rowptr, const int* __restrict__ ebuf,
                       const int* __restrict__ cnt_nr, const uint* __restrict__ W1bf,
                       const float* __restrict__ root1, const float* __restrict__ bias1,
                       float* __restrict__ h) {
  int n = blockIdx.x, t = threadIdx.x;
  if (t >= 50) return;
  float a0 = 0.f, a1 = 0.f;
  int beg = rowptr[n], end = rowptr[n + 1];
  int j = beg;
  for (; j + 1 < end; j += 2) {
    int pk0 = ebuf[j], pk1 = ebuf[j + 1];
    int r0 = pk0 & 63, s0 = pk0 >> 6;
    int r1 = pk1 & 63, s1 = pk1 >> 6;
    float c0 = 1.0f / (float)cnt_nr[n * NRELS + r0];
    float c1 = 1.0f / (float)cnt_nr[n * NRELS + r1];
    uint u0 = W1bf[(size_t)(r0 * NN + s0) * 50 + t];
    uint u1 = W1bf[(size_t)(r1 * NN + s1) * 50 + t];
    a0 += c0 * bflo(u0) + c1 * bflo(u1);
    a1 += c0 * bfhi(u0) + c1 * bfhi(u1);
  }
  if (j < end) {
    int pk = ebuf[j];
    int r = pk & 63, s = pk >> 6;
    float c = 1.0f / (float)cnt_nr[n * NRELS + r];
    uint u = W1bf[(size_t)(r * NN + s) * 50 + t];
    a0 += c * bflo(u);
    a1 += c * bfhi(u);
  }
  int c0 = 2 * t, c1 = 2 * t + 1;
  float v0 = a0 + root1[n * HID + c0] + bias1[c0];
  float v1 = a1 + root1[n * HID + c1] + bias1[c1];
  h[n * HID + c0] = v0 > 0.f ? v0 : 0.f;
  h[n * HID + c1] = v1 > 0.f ? v1 : 0.f;
}

// ---------------------------------------------------------------- hbar (packed bf16 rows)
__global__ __launch_bounds__(128) void k_hbar(const int* __restrict__ rowptr,
                                              const int* __restrict__ ebuf,
                                              const int* __restrict__ cnt_nr,
                                              const float* __restrict__ h,
                                              uint* __restrict__ hbar) { // [NROWS_PAD][KTOT/2]
  __shared__ float acc[NRELS][HID];   // 16 KB
  int n = blockIdx.x, t = threadIdx.x;
  for (int i = t; i < NRELS * HID; i += 128) ((float*)acc)[i] = 0.f;
  __syncthreads();
  if (t < HID) {
    int beg = rowptr[n], end = rowptr[n + 1];
    int j = beg;
    for (; j + 1 < end; j += 2) {
      int pk0 = ebuf[j], pk1 = ebuf[j + 1];
      int r0 = pk0 & 63, s0 = pk0 >> 6;
      int r1 = pk1 & 63, s1 = pk1 >> 6;
      float h0 = h[s0 * HID + t];
      float h1 = h[s1 * HID + t];
      acc[r0][t] += h0;
      acc[r1][t] += h1;
    }
    if (j < end) {
      int pk = ebuf[j];
      acc[pk & 63][t] += h[(pk >> 6) * HID + t];
    }
  }
  __syncthreads();
  uint* orow = hbar + (size_t)n * (KTOT / 2);
  for (int i = t; i < KTOT / 2; i += 128) {
    float v0 = 0.f, v1 = 0.f;
    if (i < R2 * 50) {
      int r = i / 50;
      int kk = (i - r * 50) * 2;
      if (r < NRELS) {
        int c = cnt_nr[n * NRELS + r];
        float coef = c ? 1.0f / (float)c : 0.f;
        v0 = acc[r][kk] * coef;
        v1 = acc[r][kk + 1] * coef;
      } else {
        v0 = h[n * HID + kk];
        v1 = h[n * HID + kk + 1];
      }
    }
    orow[i] = (uint)f2bf(v0) | ((uint)f2bf(v1) << 16);
  }
}

// ---------------------------------------------------------------- split-K MFMA GEMM
// 1 wave per block: 16 rows x 112 cols x 19 kb-steps
__global__ __launch_bounds__(64) void k_gemm(const ushort* __restrict__ hbar,
                                             const ushort* __restrict__ Bt,
                                             float* __restrict__ part) {
  int l = threadIdx.x;
  int lrow = l & 15, lk = (l >> 4) * 8;
  int kb0 = blockIdx.y * KB_PER;
  int kb1 = kb0 + KB_PER; if (kb1 > KTOT / 32) kb1 = KTOT / 32;
  int n_base = blockIdx.x * 16 + lrow;
  f32x4 acc[7];
#pragma unroll
  for (int j = 0; j < 7; ++j) acc[j] = (f32x4){0.f, 0.f, 0.f, 0.f};
  const ushort* ap = hbar + (size_t)n_base * KTOT + lk;
  const ushort* bp = Bt + (size_t)lrow * KTOT + lk;
#pragma unroll 2
  for (int kb = kb0; kb < kb1; ++kb) {
    bf16x8 a = *(const bf16x8*)(ap + kb * 32);
#pragma unroll
    for (int j = 0; j < 7; ++j) {
      bf16x8 b = *(const bf16x8*)(bp + (size_t)j * 16 * KTOT + kb * 32);
      acc[j] = __builtin_amdgcn_mfma_f32_16x16x32_bf16(a, b, acc[j], 0, 0, 0);
    }
  }
  float* pp = part + (size_t)blockIdx.y * NROWS_PAD * 112;
  int srow = blockIdx.x * 16 + (l >> 4) * 4;
#pragma unroll
  for (int j = 0; j < 7; ++j) {
    int col = j * 16 + lrow;
#pragma unroll
    for (int v = 0; v < 4; ++v)
      pp[(size_t)(srow + v) * 112 + col] = acc[j][v];
  }
}

// reduce partials + bias
__global__ void k_red(const float* __restrict__ part, const float* __restrict__ bias2,
                      float* __restrict__ xout) {
  int i = blockIdx.x * 256 + threadIdx.x;
  if (i >= NHTOT) return;
  int n = i / HID, c = i - n * HID;
  float s = bias2[c];
#pragma unroll
  for (int g = 0; g < SPLITK; ++g)
    s += part[(size_t)g * NROWS_PAD * 112 + (size_t)n * 112 + c];
  xout[i] = s;
}

// ---------------------------------------------------------------- rel_embedded
__global__ void k_emb(const float4* __restrict__ emb, const int* __restrict__ et,
                      float4* __restrict__ out2) {
  int i = blockIdx.x * 256 + threadIdx.x;
  if (i >= E_EDGES * 25) return;
  int e = i / 25, q = i - e * 25;
  int r = et[e];
  float4 v;
  if (r == 0) { v.x = 0.f; v.y = 0.f; v.z = 0.f; v.w = 0.f; }
  else v = emb[r * 25 + q];
  out2[i] = v;
}

// ---------------------------------------------------------------- launch
extern "C" void kernel_launch(void* const* d_in, const int* in_sizes, int n_in,
                              void* d_out, int out_size, void* d_ws, size_t ws_size,
                              hipStream_t stream) {
  (void)in_sizes; (void)n_in; (void)out_size; (void)d_ws; (void)ws_size;

  const float* comp1  = (const float*)d_in[0];
  const float* basis1 = (const float*)d_in[1];
  const float* root1  = (const float*)d_in[2];
  const float* bias1  = (const float*)d_in[3];
  const float* comp2  = (const float*)d_in[4];
  const float* basis2 = (const float*)d_in[5];
  const float* root2  = (const float*)d_in[6];
  const float* bias2  = (const float*)d_in[7];
  const float* emb    = (const float*)d_in[8];
  const int*   ei     = (const int*)d_in[9];
  const int*   et     = (const int*)d_in[10];
  const int* srcp = ei;
  const int* dstp = ei + E_EDGES;

  float* xout = (float*)d_out;
  float* scratch = xout + NHTOT;            // 32M floats (overwritten by k_emb last)
  int*   cnt_nr = (int*)scratch;            // @0        400,000
  int*   deg    = cnt_nr + 400000;          // @400,000   10,000
  int*   rowptr = deg + 10000;              // @410,000   10,004
  int*   fill   = rowptr + 10004;           // @420,004   10,000
  int*   ebuf   = fill + 10000;             // @430,004  320,000 -> 750,004
  float* W2f    = scratch + 750016;         // 400,000 -> 1,150,016
  ushort* Bt    = (ushort*)(scratch + 1150016);  // 112*4224 bf16 = 236,544 f -> 1,386,560
  float* h      = scratch + 1386560;        // 1,000,000 -> 2,386,560
  uint*  W1bf   = (uint*)(scratch + 2386560);    // conv1 use: 20M floats
  uint*  hbar   = (uint*)(scratch + 2386560);    // conv2 use: 10048*2112 uints = 21.22M f
  float* part   = scratch + 23607936;       // 7*10048*112 = 7,877,632 -> 31,485,568 OK

  hipMemsetAsync(cnt_nr, 0, (size_t)430004 * sizeof(int), stream);
  // zero the 48 pad rows of hbar so GEMM tail reads zeros
  hipMemsetAsync((char*)hbar + (size_t)NN * KTOT * 2, 0,
                 (size_t)(NROWS_PAD - NN) * KTOT * 2, stream);

  k_count <<<(E_EDGES + 255) / 256, 256, 0, stream>>>(dstp, et, cnt_nr, deg);
  k_scan  <<<1, 256, 0, stream>>>(deg, rowptr);
  k_bucket<<<(E_EDGES + 255) / 256, 256, 0, stream>>>(srcp, dstp, et, rowptr, fill, ebuf);

  k_w2 <<<(HID * HID + 255) / 256, 256, 0, stream>>>(comp2, basis2, W2f);
  k_bt <<<(112 * KTOT + 255) / 256, 256, 0, stream>>>(W2f, root2, Bt);
  k_w1b<<<(NHTOT / 2 + 255) / 256, 256, 0, stream>>>(comp1, basis1, W1bf);

  k_agg1<<<NN, 64, 0, stream>>>(rowptr, ebuf, cnt_nr, W1bf, root1, bias1, h);
  k_hbar<<<NN, 128, 0, stream>>>(rowptr, ebuf, cnt_nr, h, hbar);
  k_gemm<<<dim3(NROWS_PAD / 16, SPLITK), 64, 0, stream>>>((const ushort*)hbar, Bt, part);
  k_red <<<(NHTOT + 255) / 256, 256, 0, stream>>>(part, bias2, xout);

  k_emb<<<(E_EDGES * 25 + 255) / 256, 256, 0, stream>>>((const float4*)emb, et,
                                                        (float4*)(xout + NHTOT));
}

// Round 5
// 383.372 us; speedup vs baseline: 1.0855x; 1.0855x over previous
//
#include <hip/hip_runtime.h>
#include <hip/hip_bf16.h>
#include <cstdint>
#include <cstddef>

#define E_EDGES 320000
#define NN 10000
#define NRELS 40
#define NB 30
#define HID 100
#define NHTOT (NN*HID)       // 1,000,000
#define R2 41                // 40 rels + root2 slot
#define KTOT 4224            // 41*100 = 4100 packed, padded to 33*128
#define NROWS_PAD 10048      // 157 blocks * 64 rows
#define SPLITK 7             // 132 kb-steps -> 19 per gy (last 18)
#define KB_PER 19

typedef short bf16x8 __attribute__((ext_vector_type(8)));
typedef float f32x4 __attribute__((ext_vector_type(4)));

__device__ inline ushort f2bf(float f) {
  uint x = __float_as_uint(f);
  return (ushort)((x + 0x7fffu + ((x >> 16) & 1u)) >> 16);
}
__device__ inline float bflo(uint u) { return __uint_as_float(u << 16); }
__device__ inline float bfhi(uint u) { return __uint_as_float(u & 0xffff0000u); }

// ---------------------------------------------------------------- edge meta
__global__ void k_count(const int* __restrict__ dst, const int* __restrict__ et,
                        int* __restrict__ cnt_nr, int* __restrict__ deg) {
  int e = blockIdx.x * blockDim.x + threadIdx.x;
  if (e >= E_EDGES) return;
  int d = dst[e], r = et[e];
  atomicAdd(&cnt_nr[d * NRELS + r], 1);
  atomicAdd(&deg[d], 1);
}

__global__ void k_scan(const int* __restrict__ deg, int* __restrict__ rowptr) {
  __shared__ int ssum[256];
  int t = threadIdx.x;
  const int per = (NN + 255) / 256;
  int base = t * per;
  int s = 0;
  for (int k = 0; k < per; ++k) { int i = base + k; if (i < NN) s += deg[i]; }
  ssum[t] = s; __syncthreads();
  for (int off = 1; off < 256; off <<= 1) {
    int v = (t >= off) ? ssum[t - off] : 0;
    __syncthreads();
    ssum[t] += v;
    __syncthreads();
  }
  int pre = (t == 0) ? 0 : ssum[t - 1];
  for (int k = 0; k < per; ++k) {
    int i = base + k;
    if (i < NN) { rowptr[i] = pre; pre += deg[i]; }
  }
  if (t == 255) rowptr[NN] = ssum[255];
}

__global__ void k_bucket(const int* __restrict__ src, const int* __restrict__ dst,
                         const int* __restrict__ et, const int* __restrict__ rowptr,
                         int* __restrict__ fill, int* __restrict__ ebuf) {
  int e = blockIdx.x * blockDim.x + threadIdx.x;
  if (e >= E_EDGES) return;
  int d = dst[e];
  int pos = rowptr[d] + atomicAdd(&fill[d], 1);
  ebuf[pos] = (src[e] << 6) | et[e];
}

// ---------------------------------------------------------------- W1 (bf16, all 40 rels)
// Loop-interchanged: thread's live state = 80 fp32 ACCUMULATORS (won't be
// rematerialized/spilled, unlike a cached-loads array); basis1 streamed once.
// comp1 via LDS all-lane-broadcast float4 reads.
__global__ __launch_bounds__(256, 2) void k_w1b(const float* __restrict__ comp1,
                                                const float* __restrict__ basis1,
                                                uint* __restrict__ W1bf) {
  __shared__ float sct[NB][NRELS];   // comp1 transposed: [b][r]
  int t = threadIdx.x;
  for (int i = t; i < NRELS * NB; i += 256) {
    int r = i / NB, b = i - r * NB;
    sct[b][r] = comp1[i];
  }
  __syncthreads();
  int i2 = blockIdx.x * 256 + t;
  if (i2 >= NHTOT / 2) return;
  float ax[NRELS], ay[NRELS];
#pragma unroll
  for (int r = 0; r < NRELS; ++r) { ax[r] = 0.f; ay[r] = 0.f; }
  for (int b = 0; b < NB; ++b) {
    float2 v = ((const float2*)basis1)[(size_t)b * (NHTOT / 2) + i2];
#pragma unroll
    for (int r4 = 0; r4 < NRELS / 4; ++r4) {
      float4 c = *(const float4*)&sct[b][r4 * 4];   // broadcast ds_read_b128
      ax[r4*4+0] += c.x * v.x; ay[r4*4+0] += c.x * v.y;
      ax[r4*4+1] += c.y * v.x; ay[r4*4+1] += c.y * v.y;
      ax[r4*4+2] += c.z * v.x; ay[r4*4+2] += c.z * v.y;
      ax[r4*4+3] += c.w * v.x; ay[r4*4+3] += c.w * v.y;
    }
  }
#pragma unroll
  for (int r = 0; r < NRELS; ++r)
    W1bf[(size_t)r * (NHTOT / 2) + i2] = (uint)f2bf(ax[r]) | ((uint)f2bf(ay[r]) << 16);
}

// ---------------------------------------------------------------- W2 fp32 then packed Bt bf16
__global__ void k_w2(const float* __restrict__ comp2, const float* __restrict__ basis2,
                     float* __restrict__ W2f) {
  int i = blockIdx.x * 256 + threadIdx.x;
  if (i >= HID * HID) return;
  float v[NB];
#pragma unroll
  for (int b = 0; b < NB; ++b) v[b] = basis2[b * HID * HID + i];
  for (int r = 0; r < NRELS; ++r) {
    float a = 0.f;
#pragma unroll
    for (int b = 0; b < NB; ++b) a += comp2[r * NB + b] * v[b];
    W2f[r * HID * HID + i] = a;
  }
}

// Bt[col][kk] packed K: kk = r*100 + k  (r<40: W2f[r][k][col], r==40: root2[k][col])
__global__ void k_bt(const float* __restrict__ W2f, const float* __restrict__ root2,
                     ushort* __restrict__ Bt) {
  int i = blockIdx.x * 256 + threadIdx.x;
  if (i >= 112 * KTOT) return;
  int col = i / KTOT, kk = i - col * KTOT;
  float v = 0.f;
  if (kk < R2 * HID && col < HID) {
    int r = kk / HID, k = kk - r * HID;
    v = (r < NRELS) ? W2f[(r * HID + k) * HID + col] : root2[k * HID + col];
  }
  Bt[i] = f2bf(v);
}

// ---------------------------------------------------------------- conv1 aggregate
__global__ void k_agg1(const int* __restrict__ rowptr, const int* __restrict__ ebuf,
                       const int* __restrict__ cnt_nr, const uint* __restrict__ W1bf,
                       const float* __restrict__ root1, const float* __restrict__ bias1,
                       float* __restrict__ h) {
  int n = blockIdx.x, t = threadIdx.x;
  if (t >= 50) return;
  float a0 = 0.f, a1 = 0.f;
  int beg = rowptr[n], end = rowptr[n + 1];
  int j = beg;
  for (; j + 1 < end; j += 2) {
    int pk0 = ebuf[j], pk1 = ebuf[j + 1];
    int r0 = pk0 & 63, s0 = pk0 >> 6;
    int r1 = pk1 & 63, s1 = pk1 >> 6;
    float c0 = 1.0f / (float)cnt_nr[n * NRELS + r0];
    float c1 = 1.0f / (float)cnt_nr[n * NRELS + r1];
    uint u0 = W1bf[(size_t)(r0 * NN + s0) * 50 + t];
    uint u1 = W1bf[(size_t)(r1 * NN + s1) * 50 + t];
    a0 += c0 * bflo(u0) + c1 * bflo(u1);
    a1 += c0 * bfhi(u0) + c1 * bfhi(u1);
  }
  if (j < end) {
    int pk = ebuf[j];
    int r = pk & 63, s = pk >> 6;
    float c = 1.0f / (float)cnt_nr[n * NRELS + r];
    uint u = W1bf[(size_t)(r * NN + s) * 50 + t];
    a0 += c * bflo(u);
    a1 += c * bfhi(u);
  }
  int c0 = 2 * t, c1 = 2 * t + 1;
  float v0 = a0 + root1[n * HID + c0] + bias1[c0];
  float v1 = a1 + root1[n * HID + c1] + bias1[c1];
  h[n * HID + c0] = v0 > 0.f ? v0 : 0.f;
  h[n * HID + c1] = v1 > 0.f ? v1 : 0.f;
}

// ---------------------------------------------------------------- hbar (packed bf16 rows)
__global__ __launch_bounds__(128) void k_hbar(const int* __restrict__ rowptr,
                                              const int* __restrict__ ebuf,
                                              const int* __restrict__ cnt_nr,
                                              const float* __restrict__ h,
                                              uint* __restrict__ hbar) { // [NROWS_PAD][KTOT/2]
  __shared__ float acc[NRELS][HID];   // 16 KB
  int n = blockIdx.x, t = threadIdx.x;
  for (int i = t; i < NRELS * HID; i += 128) ((float*)acc)[i] = 0.f;
  __syncthreads();
  if (t < HID) {
    int beg = rowptr[n], end = rowptr[n + 1];
    int j = beg;
    for (; j + 1 < end; j += 2) {
      int pk0 = ebuf[j], pk1 = ebuf[j + 1];
      int r0 = pk0 & 63, s0 = pk0 >> 6;
      int r1 = pk1 & 63, s1 = pk1 >> 6;
      float h0 = h[s0 * HID + t];
      float h1 = h[s1 * HID + t];
      acc[r0][t] += h0;
      acc[r1][t] += h1;
    }
    if (j < end) {
      int pk = ebuf[j];
      acc[pk & 63][t] += h[(pk >> 6) * HID + t];
    }
  }
  __syncthreads();
  uint* orow = hbar + (size_t)n * (KTOT / 2);
  for (int i = t; i < KTOT / 2; i += 128) {
    float v0 = 0.f, v1 = 0.f;
    if (i < R2 * 50) {
      int r = i / 50;
      int kk = (i - r * 50) * 2;
      if (r < NRELS) {
        int c = cnt_nr[n * NRELS + r];
        float coef = c ? 1.0f / (float)c : 0.f;
        v0 = acc[r][kk] * coef;
        v1 = acc[r][kk + 1] * coef;
      } else {
        v0 = h[n * HID + kk];
        v1 = h[n * HID + kk + 1];
      }
    }
    orow[i] = (uint)f2bf(v0) | ((uint)f2bf(v1) << 16);
  }
}

// ---------------------------------------------------------------- split-K MFMA GEMM
// r3 shape (4 waves/block, 16 rows/wave) + 256-VGPR headroom so all 8 fragment
// loads stay in flight (r3's VGPR=40 cap serialized load->wait->MFMA; r4's
// 1-wave variant spilled acc under the default cap).
__global__ __launch_bounds__(256, 2) void k_gemm(const ushort* __restrict__ hbar,
                                                 const ushort* __restrict__ Bt,
                                                 float* __restrict__ part) {
  int t = threadIdx.x;
  int wid = t >> 6, l = t & 63;
  int lrow = l & 15, lk = (l >> 4) * 8;
  int kb0 = blockIdx.y * KB_PER;
  int kb1 = kb0 + KB_PER; if (kb1 > KTOT / 32) kb1 = KTOT / 32;
  int n_base = blockIdx.x * 64 + wid * 16 + lrow;
  f32x4 acc[7];
#pragma unroll
  for (int j = 0; j < 7; ++j) acc[j] = (f32x4){0.f, 0.f, 0.f, 0.f};
  const ushort* ap = hbar + (size_t)n_base * KTOT + lk;
  const ushort* bp = Bt + (size_t)lrow * KTOT + lk;
#pragma unroll 2
  for (int kb = kb0; kb < kb1; ++kb) {
    bf16x8 a = *(const bf16x8*)(ap + kb * 32);
    bf16x8 b0 = *(const bf16x8*)(bp + (size_t)0 * 16 * KTOT + kb * 32);
    bf16x8 b1 = *(const bf16x8*)(bp + (size_t)1 * 16 * KTOT + kb * 32);
    bf16x8 b2 = *(const bf16x8*)(bp + (size_t)2 * 16 * KTOT + kb * 32);
    bf16x8 b3 = *(const bf16x8*)(bp + (size_t)3 * 16 * KTOT + kb * 32);
    bf16x8 b4 = *(const bf16x8*)(bp + (size_t)4 * 16 * KTOT + kb * 32);
    bf16x8 b5 = *(const bf16x8*)(bp + (size_t)5 * 16 * KTOT + kb * 32);
    bf16x8 b6 = *(const bf16x8*)(bp + (size_t)6 * 16 * KTOT + kb * 32);
    acc[0] = __builtin_amdgcn_mfma_f32_16x16x32_bf16(a, b0, acc[0], 0, 0, 0);
    acc[1] = __builtin_amdgcn_mfma_f32_16x16x32_bf16(a, b1, acc[1], 0, 0, 0);
    acc[2] = __builtin_amdgcn_mfma_f32_16x16x32_bf16(a, b2, acc[2], 0, 0, 0);
    acc[3] = __builtin_amdgcn_mfma_f32_16x16x32_bf16(a, b3, acc[3], 0, 0, 0);
    acc[4] = __builtin_amdgcn_mfma_f32_16x16x32_bf16(a, b4, acc[4], 0, 0, 0);
    acc[5] = __builtin_amdgcn_mfma_f32_16x16x32_bf16(a, b5, acc[5], 0, 0, 0);
    acc[6] = __builtin_amdgcn_mfma_f32_16x16x32_bf16(a, b6, acc[6], 0, 0, 0);
  }
  float* pp = part + (size_t)blockIdx.y * NROWS_PAD * 112;
  int srow = blockIdx.x * 64 + wid * 16 + (l >> 4) * 4;
#pragma unroll
  for (int j = 0; j < 7; ++j) {
    int col = j * 16 + lrow;
#pragma unroll
    for (int v = 0; v < 4; ++v)
      pp[(size_t)(srow + v) * 112 + col] = acc[j][v];
  }
}

// reduce partials + bias
__global__ void k_red(const float* __restrict__ part, const float* __restrict__ bias2,
                      float* __restrict__ xout) {
  int i = blockIdx.x * 256 + threadIdx.x;
  if (i >= NHTOT) return;
  int n = i / HID, c = i - n * HID;
  float s = bias2[c];
#pragma unroll
  for (int g = 0; g < SPLITK; ++g)
    s += part[(size_t)g * NROWS_PAD * 112 + (size_t)n * 112 + c];
  xout[i] = s;
}

// ---------------------------------------------------------------- rel_embedded
__global__ void k_emb(const float4* __restrict__ emb, const int* __restrict__ et,
                      float4* __restrict__ out2) {
  int i = blockIdx.x * 256 + threadIdx.x;
  if (i >= E_EDGES * 25) return;
  int e = i / 25, q = i - e * 25;
  int r = et[e];
  float4 v;
  if (r == 0) { v.x = 0.f; v.y = 0.f; v.z = 0.f; v.w = 0.f; }
  else v = emb[r * 25 + q];
  out2[i] = v;
}

// ---------------------------------------------------------------- launch
extern "C" void kernel_launch(void* const* d_in, const int* in_sizes, int n_in,
                              void* d_out, int out_size, void* d_ws, size_t ws_size,
                              hipStream_t stream) {
  (void)in_sizes; (void)n_in; (void)out_size; (void)d_ws; (void)ws_size;

  const float* comp1  = (const float*)d_in[0];
  const float* basis1 = (const float*)d_in[1];
  const float* root1  = (const float*)d_in[2];
  const float* bias1  = (const float*)d_in[3];
  const float* comp2  = (const float*)d_in[4];
  const float* basis2 = (const float*)d_in[5];
  const float* root2  = (const float*)d_in[6];
  const float* bias2  = (const float*)d_in[7];
  const float* emb    = (const float*)d_in[8];
  const int*   ei     = (const int*)d_in[9];
  const int*   et     = (const int*)d_in[10];
  const int* srcp = ei;
  const int* dstp = ei + E_EDGES;

  float* xout = (float*)d_out;
  float* scratch = xout + NHTOT;            // 32M floats (overwritten by k_emb last)
  int*   cnt_nr = (int*)scratch;            // @0        400,000
  int*   deg    = cnt_nr + 400000;          // @400,000   10,000
  int*   rowptr = deg + 10000;              // @410,000   10,004
  int*   fill   = rowptr + 10004;           // @420,004   10,000
  int*   ebuf   = fill + 10000;             // @430,004  320,000 -> 750,004
  float* W2f    = scratch + 750016;         // 400,000 -> 1,150,016
  ushort* Bt    = (ushort*)(scratch + 1150016);  // 112*4224 bf16 = 236,544 f -> 1,386,560
  float* h      = scratch + 1386560;        // 1,000,000 -> 2,386,560
  uint*  W1bf   = (uint*)(scratch + 2386560);    // conv1 use: 20M floats
  uint*  hbar   = (uint*)(scratch + 2386560);    // conv2 use: 10048*2112 uints = 21.22M f
  float* part   = scratch + 23607936;       // 7*10048*112 = 7,877,632 -> 31,485,568 OK

  hipMemsetAsync(cnt_nr, 0, (size_t)430004 * sizeof(int), stream);
  // zero the 48 pad rows of hbar so GEMM tail reads zeros
  hipMemsetAsync((char*)hbar + (size_t)NN * KTOT * 2, 0,
                 (size_t)(NROWS_PAD - NN) * KTOT * 2, stream);

  k_count <<<(E_EDGES + 255) / 256, 256, 0, stream>>>(dstp, et, cnt_nr, deg);
  k_scan  <<<1, 256, 0, stream>>>(deg, rowptr);
  k_bucket<<<(E_EDGES + 255) / 256, 256, 0, stream>>>(srcp, dstp, et, rowptr, fill, ebuf);

  k_w2 <<<(HID * HID + 255) / 256, 256, 0, stream>>>(comp2, basis2, W2f);
  k_bt <<<(112 * KTOT + 255) / 256, 256, 0, stream>>>(W2f, root2, Bt);
  k_w1b<<<(NHTOT / 2 + 255) / 256, 256, 0, stream>>>(comp1, basis1, W1bf);

  k_agg1<<<NN, 64, 0, stream>>>(rowptr, ebuf, cnt_nr, W1bf, root1, bias1, h);
  k_hbar<<<NN, 128, 0, stream>>>(rowptr, ebuf, cnt_nr, h, hbar);
  k_gemm<<<dim3(NROWS_PAD / 64, SPLITK), 256, 0, stream>>>((const ushort*)hbar, Bt, part);
  k_red <<<(NHTOT + 255) / 256, 256, 0, stream>>>(part, bias2, xout);

  k_emb<<<(E_EDGES * 25 + 255) / 256, 256, 0, stream>>>((const float4*)emb, et,
                                                        (float4*)(xout + NHTOT));
}

// Round 6
// 299.767 us; speedup vs baseline: 1.3883x; 1.2789x over previous
//
#include <hip/hip_runtime.h>
#include <hip/hip_bf16.h>
#include <cstdint>
#include <cstddef>

#define E_EDGES 320000
#define NN 10000
#define NRELS 40
#define NB 30
#define HID 100
#define NHTOT (NN*HID)       // 1,000,000
#define R2 41                // 40 rels + root2 slot
#define KTOT 4224            // 41*100 = 4100 packed, padded to 33*128
#define NROWS_PAD 10048      // 157 blocks * 64 rows
#define SPLITK 4             // 132 kb-steps -> 33 per gy
#define KB_PER 33

typedef short bf16x8 __attribute__((ext_vector_type(8)));
typedef float f32x4 __attribute__((ext_vector_type(4)));

__device__ inline ushort f2bf(float f) {
  uint x = __float_as_uint(f);
  return (ushort)((x + 0x7fffu + ((x >> 16) & 1u)) >> 16);
}
__device__ inline float bflo(uint u) { return __uint_as_float(u << 16); }
__device__ inline float bfhi(uint u) { return __uint_as_float(u & 0xffff0000u); }

__device__ inline void gload16(const void* g, void* l) {
  __builtin_amdgcn_global_load_lds(
      (const __attribute__((address_space(1))) void*)g,
      (__attribute__((address_space(3))) void*)l, 16, 0, 0);
}

// ---------------------------------------------------------------- edge meta
__global__ void k_count(const int* __restrict__ dst, const int* __restrict__ et,
                        int* __restrict__ cnt_nr, int* __restrict__ deg) {
  int e = blockIdx.x * blockDim.x + threadIdx.x;
  if (e >= E_EDGES) return;
  int d = dst[e], r = et[e];
  atomicAdd(&cnt_nr[d * NRELS + r], 1);
  atomicAdd(&deg[d], 1);
}

__global__ void k_scan(const int* __restrict__ deg, int* __restrict__ rowptr) {
  __shared__ int ssum[256];
  int t = threadIdx.x;
  const int per = (NN + 255) / 256;
  int base = t * per;
  int s = 0;
  for (int k = 0; k < per; ++k) { int i = base + k; if (i < NN) s += deg[i]; }
  ssum[t] = s; __syncthreads();
  for (int off = 1; off < 256; off <<= 1) {
    int v = (t >= off) ? ssum[t - off] : 0;
    __syncthreads();
    ssum[t] += v;
    __syncthreads();
  }
  int pre = (t == 0) ? 0 : ssum[t - 1];
  for (int k = 0; k < per; ++k) {
    int i = base + k;
    if (i < NN) { rowptr[i] = pre; pre += deg[i]; }
  }
  if (t == 255) rowptr[NN] = ssum[255];
}

__global__ void k_bucket(const int* __restrict__ src, const int* __restrict__ dst,
                         const int* __restrict__ et, const int* __restrict__ rowptr,
                         int* __restrict__ fill, int* __restrict__ ebuf) {
  int e = blockIdx.x * blockDim.x + threadIdx.x;
  if (e >= E_EDGES) return;
  int d = dst[e];
  int pos = rowptr[d] + atomicAdd(&fill[d], 1);
  ebuf[pos] = (src[e] << 6) | et[e];
}

// ---------------------------------------------------------------- W1 (bf16, all 40 rels)
__global__ __launch_bounds__(256, 2) void k_w1b(const float* __restrict__ comp1,
                                                const float* __restrict__ basis1,
                                                uint* __restrict__ W1bf) {
  __shared__ float sct[NB][NRELS];   // comp1 transposed: [b][r]
  int t = threadIdx.x;
  for (int i = t; i < NRELS * NB; i += 256) {
    int r = i / NB, b = i - r * NB;
    sct[b][r] = comp1[i];
  }
  __syncthreads();
  int i2 = blockIdx.x * 256 + t;
  if (i2 >= NHTOT / 2) return;
  float ax[NRELS], ay[NRELS];
#pragma unroll
  for (int r = 0; r < NRELS; ++r) { ax[r] = 0.f; ay[r] = 0.f; }
  for (int b = 0; b < NB; ++b) {
    float2 v = ((const float2*)basis1)[(size_t)b * (NHTOT / 2) + i2];
#pragma unroll
    for (int r4 = 0; r4 < NRELS / 4; ++r4) {
      float4 c = *(const float4*)&sct[b][r4 * 4];   // broadcast ds_read_b128
      ax[r4*4+0] += c.x * v.x; ay[r4*4+0] += c.x * v.y;
      ax[r4*4+1] += c.y * v.x; ay[r4*4+1] += c.y * v.y;
      ax[r4*4+2] += c.z * v.x; ay[r4*4+2] += c.z * v.y;
      ax[r4*4+3] += c.w * v.x; ay[r4*4+3] += c.w * v.y;
    }
  }
#pragma unroll
  for (int r = 0; r < NRELS; ++r)
    W1bf[(size_t)r * (NHTOT / 2) + i2] = (uint)f2bf(ax[r]) | ((uint)f2bf(ay[r]) << 16);
}

// ---------------------------------------------------------------- W2 fp32 then packed Bt bf16
__global__ void k_w2(const float* __restrict__ comp2, const float* __restrict__ basis2,
                     float* __restrict__ W2f) {
  int i = blockIdx.x * 256 + threadIdx.x;
  if (i >= HID * HID) return;
  float v[NB];
#pragma unroll
  for (int b = 0; b < NB; ++b) v[b] = basis2[b * HID * HID + i];
  for (int r = 0; r < NRELS; ++r) {
    float a = 0.f;
#pragma unroll
    for (int b = 0; b < NB; ++b) a += comp2[r * NB + b] * v[b];
    W2f[r * HID * HID + i] = a;
  }
}

// Bt[col][kk] packed K: kk = r*100 + k  (r<40: W2f[r][k][col], r==40: root2[k][col])
__global__ void k_bt(const float* __restrict__ W2f, const float* __restrict__ root2,
                     ushort* __restrict__ Bt) {
  int i = blockIdx.x * 256 + threadIdx.x;
  if (i >= 112 * KTOT) return;
  int col = i / KTOT, kk = i - col * KTOT;
  float v = 0.f;
  if (kk < R2 * HID && col < HID) {
    int r = kk / HID, k = kk - r * HID;
    v = (r < NRELS) ? W2f[(r * HID + k) * HID + col] : root2[k * HID + col];
  }
  Bt[i] = f2bf(v);
}

// ---------------------------------------------------------------- conv1 aggregate
__global__ void k_agg1(const int* __restrict__ rowptr, const int* __restrict__ ebuf,
                       const int* __restrict__ cnt_nr, const uint* __restrict__ W1bf,
                       const float* __restrict__ root1, const float* __restrict__ bias1,
                       float* __restrict__ h) {
  int n = blockIdx.x, t = threadIdx.x;
  if (t >= 50) return;
  float a0 = 0.f, a1 = 0.f;
  int beg = rowptr[n], end = rowptr[n + 1];
  int j = beg;
  for (; j + 1 < end; j += 2) {
    int pk0 = ebuf[j], pk1 = ebuf[j + 1];
    int r0 = pk0 & 63, s0 = pk0 >> 6;
    int r1 = pk1 & 63, s1 = pk1 >> 6;
    float c0 = 1.0f / (float)cnt_nr[n * NRELS + r0];
    float c1 = 1.0f / (float)cnt_nr[n * NRELS + r1];
    uint u0 = W1bf[(size_t)(r0 * NN + s0) * 50 + t];
    uint u1 = W1bf[(size_t)(r1 * NN + s1) * 50 + t];
    a0 += c0 * bflo(u0) + c1 * bflo(u1);
    a1 += c0 * bfhi(u0) + c1 * bfhi(u1);
  }
  if (j < end) {
    int pk = ebuf[j];
    int r = pk & 63, s = pk >> 6;
    float c = 1.0f / (float)cnt_nr[n * NRELS + r];
    uint u = W1bf[(size_t)(r * NN + s) * 50 + t];
    a0 += c * bflo(u);
    a1 += c * bfhi(u);
  }
  int c0 = 2 * t, c1 = 2 * t + 1;
  float v0 = a0 + root1[n * HID + c0] + bias1[c0];
  float v1 = a1 + root1[n * HID + c1] + bias1[c1];
  h[n * HID + c0] = v0 > 0.f ? v0 : 0.f;
  h[n * HID + c1] = v1 > 0.f ? v1 : 0.f;
}

// ---------------------------------------------------------------- hbar (packed bf16 rows)
__global__ __launch_bounds__(128) void k_hbar(const int* __restrict__ rowptr,
                                              const int* __restrict__ ebuf,
                                              const int* __restrict__ cnt_nr,
                                              const float* __restrict__ h,
                                              uint* __restrict__ hbar) { // [NROWS_PAD][KTOT/2]
  __shared__ float acc[NRELS][HID];   // 16 KB
  int n = blockIdx.x, t = threadIdx.x;
  for (int i = t; i < NRELS * HID; i += 128) ((float*)acc)[i] = 0.f;
  __syncthreads();
  if (t < HID) {
    int beg = rowptr[n], end = rowptr[n + 1];
    int j = beg;
    for (; j + 1 < end; j += 2) {
      int pk0 = ebuf[j], pk1 = ebuf[j + 1];
      int r0 = pk0 & 63, s0 = pk0 >> 6;
      int r1 = pk1 & 63, s1 = pk1 >> 6;
      float h0 = h[s0 * HID + t];
      float h1 = h[s1 * HID + t];
      acc[r0][t] += h0;
      acc[r1][t] += h1;
    }
    if (j < end) {
      int pk = ebuf[j];
      acc[pk & 63][t] += h[(pk >> 6) * HID + t];
    }
  }
  __syncthreads();
  uint* orow = hbar + (size_t)n * (KTOT / 2);
  for (int i = t; i < KTOT / 2; i += 128) {
    float v0 = 0.f, v1 = 0.f;
    if (i < R2 * 50) {
      int r = i / 50;
      int kk = (i - r * 50) * 2;
      if (r < NRELS) {
        int c = cnt_nr[n * NRELS + r];
        float coef = c ? 1.0f / (float)c : 0.f;
        v0 = acc[r][kk] * coef;
        v1 = acc[r][kk + 1] * coef;
      } else {
        v0 = h[n * HID + kk];
        v1 = h[n * HID + kk + 1];
      }
    }
    orow[i] = (uint)f2bf(v0) | ((uint)f2bf(v1) << 16);
  }
}

// ---------------------------------------------------------------- split-K MFMA GEMM
// 2-phase double-buffered LDS pipeline (guide §5.5 T3-minimum): stage next
// 32-K slice of A(64 rows)+B(112 cols) via global_load_lds while MFMAing the
// current slice from LDS. Latency hidden by async DMA, not register ILP
// (r4/r5: compiler allocated 32 VGPR and serialized the 7 B-loads -> 91us).
// LDS layout linear, row stride 64B -> b128 start-banks uniform mod 128B ->
// bank-optimal, no swizzle. Chunks: B=448 (col*4+c), A=256 (+448), pad->768.
__global__ __launch_bounds__(256) void k_gemm(const ushort* __restrict__ hbar,
                                              const ushort* __restrict__ Bt,
                                              float* __restrict__ part) {
  __shared__ char lds[2][12288];
  int t = threadIdx.x;
  int wid = t >> 6, l = t & 63;
  int lrow = l & 15, g16 = l >> 4;
  int kb0 = blockIdx.y * KB_PER;
  int row0 = blockIdx.x * 64;

  f32x4 acc[7];
#pragma unroll
  for (int j = 0; j < 7; ++j) acc[j] = (f32x4){0.f, 0.f, 0.f, 0.f};

  // --- stage phase p (kb = kb0+p) into buffer buf
  auto stage = [&](int p, int buf) {
    int kbg = kb0 + p;
#pragma unroll
    for (int ci = 0; ci < 3; ++ci) {
      int qb = (wid * 3 + ci) * 64;
      int q = qb + l;
      const ushort* g;
      if (q < 448) {                       // B chunk (wave-uniform branch: 448=7*64)
        int col = q >> 2, c = q & 3;
        g = Bt + (size_t)col * KTOT + kbg * 32 + c * 8;
      } else if (q < 704) {                // A chunk (704=11*64)
        int qq = q - 448;
        int row = qq >> 2, c = qq & 3;
        g = hbar + (size_t)(row0 + row) * KTOT + kbg * 32 + c * 8;
      } else {                             // pad (written to LDS pad, never read)
        g = Bt;
      }
      gload16(g, &lds[buf][(size_t)qb * 16]);
    }
  };

  stage(0, 0);
  __syncthreads();

  int cur = 0;
  for (int p = 0; p < KB_PER; ++p) {
    if (p + 1 < KB_PER) stage(p + 1, cur ^ 1);
    const char* base = lds[cur];
    bf16x8 a = *(const bf16x8*)(base + 7168 + (wid * 16 + lrow) * 64 + g16 * 16);
#pragma unroll
    for (int j = 0; j < 7; ++j) {
      bf16x8 b = *(const bf16x8*)(base + (j * 16 + lrow) * 64 + g16 * 16);
      acc[j] = __builtin_amdgcn_mfma_f32_16x16x32_bf16(a, b, acc[j], 0, 0, 0);
    }
    __syncthreads();   // waits vmcnt(0) lgkmcnt(0): staged buf^1 ready, reads done
    cur ^= 1;
  }

  float* pp = part + (size_t)blockIdx.y * NROWS_PAD * 112;
  int srow = row0 + wid * 16 + g16 * 4;
#pragma unroll
  for (int j = 0; j < 7; ++j) {
    int col = j * 16 + lrow;
#pragma unroll
    for (int v = 0; v < 4; ++v)
      pp[(size_t)(srow + v) * 112 + col] = acc[j][v];
  }
}

// reduce partials + bias
__global__ void k_red(const float* __restrict__ part, const float* __restrict__ bias2,
                      float* __restrict__ xout) {
  int i = blockIdx.x * 256 + threadIdx.x;
  if (i >= NHTOT) return;
  int n = i / HID, c = i - n * HID;
  float s = bias2[c];
#pragma unroll
  for (int g = 0; g < SPLITK; ++g)
    s += part[(size_t)g * NROWS_PAD * 112 + (size_t)n * 112 + c];
  xout[i] = s;
}

// ---------------------------------------------------------------- rel_embedded
__global__ void k_emb(const float4* __restrict__ emb, const int* __restrict__ et,
                      float4* __restrict__ out2) {
  int i = blockIdx.x * 256 + threadIdx.x;
  if (i >= E_EDGES * 25) return;
  int e = i / 25, q = i - e * 25;
  int r = et[e];
  float4 v;
  if (r == 0) { v.x = 0.f; v.y = 0.f; v.z = 0.f; v.w = 0.f; }
  else v = emb[r * 25 + q];
  out2[i] = v;
}

// ---------------------------------------------------------------- launch
extern "C" void kernel_launch(void* const* d_in, const int* in_sizes, int n_in,
                              void* d_out, int out_size, void* d_ws, size_t ws_size,
                              hipStream_t stream) {
  (void)in_sizes; (void)n_in; (void)out_size; (void)d_ws; (void)ws_size;

  const float* comp1  = (const float*)d_in[0];
  const float* basis1 = (const float*)d_in[1];
  const float* root1  = (const float*)d_in[2];
  const float* bias1  = (const float*)d_in[3];
  const float* comp2  = (const float*)d_in[4];
  const float* basis2 = (const float*)d_in[5];
  const float* root2  = (const float*)d_in[6];
  const float* bias2  = (const float*)d_in[7];
  const float* emb    = (const float*)d_in[8];
  const int*   ei     = (const int*)d_in[9];
  const int*   et     = (const int*)d_in[10];
  const int* srcp = ei;
  const int* dstp = ei + E_EDGES;

  float* xout = (float*)d_out;
  float* scratch = xout + NHTOT;            // 32M floats (overwritten by k_emb last)
  int*   cnt_nr = (int*)scratch;            // @0        400,000
  int*   deg    = cnt_nr + 400000;          // @400,000   10,000
  int*   rowptr = deg + 10000;              // @410,000   10,004
  int*   fill   = rowptr + 10004;           // @420,004   10,000
  int*   ebuf   = fill + 10000;             // @430,004  320,000 -> 750,004
  float* W2f    = scratch + 750016;         // 400,000 -> 1,150,016
  ushort* Bt    = (ushort*)(scratch + 1150016);  // 112*4224 bf16 = 236,544 f -> 1,386,560
  float* h      = scratch + 1386560;        // 1,000,000 -> 2,386,560
  uint*  W1bf   = (uint*)(scratch + 2386560);    // conv1 use: 20M floats
  uint*  hbar   = (uint*)(scratch + 2386560);    // conv2 use: 10048*2112 uints = 21.22M f
  float* part   = scratch + 23607936;       // 4*10048*112 = 4,501,504 -> 28,109,440 OK

  hipMemsetAsync(cnt_nr, 0, (size_t)430004 * sizeof(int), stream);
  // zero the 48 pad rows of hbar so GEMM tail reads zeros
  hipMemsetAsync((char*)hbar + (size_t)NN * KTOT * 2, 0,
                 (size_t)(NROWS_PAD - NN) * KTOT * 2, stream);

  k_count <<<(E_EDGES + 255) / 256, 256, 0, stream>>>(dstp, et, cnt_nr, deg);
  k_scan  <<<1, 256, 0, stream>>>(deg, rowptr);
  k_bucket<<<(E_EDGES + 255) / 256, 256, 0, stream>>>(srcp, dstp, et, rowptr, fill, ebuf);

  k_w2 <<<(HID * HID + 255) / 256, 256, 0, stream>>>(comp2, basis2, W2f);
  k_bt <<<(112 * KTOT + 255) / 256, 256, 0, stream>>>(W2f, root2, Bt);
  k_w1b<<<(NHTOT / 2 + 255) / 256, 256, 0, stream>>>(comp1, basis1, W1bf);

  k_agg1<<<NN, 64, 0, stream>>>(rowptr, ebuf, cnt_nr, W1bf, root1, bias1, h);
  k_hbar<<<NN, 128, 0, stream>>>(rowptr, ebuf, cnt_nr, h, hbar);
  k_gemm<<<dim3(NROWS_PAD / 64, SPLITK), 256, 0, stream>>>((const ushort*)hbar, Bt, part);
  k_red <<<(NHTOT + 255) / 256, 256, 0, stream>>>(part, bias2, xout);

  k_emb<<<(E_EDGES * 25 + 255) / 256, 256, 0, stream>>>((const float4*)emb, et,
                                                        (float4*)(xout + NHTOT));
}